// Round 8
// baseline (371.665 us; speedup 1.0000x reference)
//
#include <hip/hip_runtime.h>
#include <hip/hip_bf16.h>
#include <stdint.h>

#define RES 512
#define CH  32
#define NP  3
#define NTEX (NP * RES * RES)                             // 786432 texels
#define NT2  (NTEX / 2)                                   // texel pairs
#define TEX_BYTES ((size_t)NTEX * CH * sizeof(uint16_t))  // 48 MiB (bf16 ws)
#define BGRID 16                                          // bins per axis
#define NBIN  (BGRID * BGRID * BGRID)                     // 4096
#define HBLK  16384                                       // points per hist/scatter block
#define TGRID (NT2 / 1024)                                // 384 transpose blocks in k_prep
#define GBLOCKS 2048                                      // persistent gather blocks (8/CU)

typedef float vfloat4 __attribute__((ext_vector_type(4)));
typedef float vfloat2 __attribute__((ext_vector_type(2)));

static __device__ __forceinline__ uint16_t f2bf(float f) {
    union { float f; uint32_t u; } v; v.f = f;
    uint32_t u = v.u;
    uint32_t r = (u + 0x7fffu + ((u >> 16) & 1u)) >> 16;   // RNE
    return (uint16_t)r;
}

static __device__ __forceinline__ int binq(float c) {
    int v = (int)floorf((c + 1.f) * (BGRID * 0.5f));
    return min(BGRID - 1, max(0, v));
}
// Morton/Z-order bin id: consecutive bins are 3D neighbors -> consecutive
// gather chunks' plane footprints overlap in ALL THREE projections.
static __device__ __forceinline__ uint32_t spread3(uint32_t v) {   // 4-bit -> bits 0,3,6,9
    return (v & 1u) | ((v & 2u) << 2) | ((v & 4u) << 4) | ((v & 8u) << 6);
}
static __device__ __forceinline__ int bin_of(float cx, float cy, float cz) {
    return (int)(spread3((uint32_t)binq(cx)) | (spread3((uint32_t)binq(cy)) << 1)
                 | (spread3((uint32_t)binq(cz)) << 2));
}

// ---------------------------------------------------------------------------
// Shared transpose body: texel pair t2 -> [3][R][R][C] bf16, clipped.
// ---------------------------------------------------------------------------
static __device__ __forceinline__ void transpose_body(const float* __restrict__ tri,
                                                      uint16_t* __restrict__ ws, int t2) {
    int xp = t2 & (RES / 2 - 1);
    int y  = (t2 >> 8) & (RES - 1);
    int p  = t2 >> 17;
    int x  = xp * 2;
    const float* src = tri + (size_t)p * CH * RES * RES + (size_t)y * RES + x;
    uint32_t pa[16], pb[16];
#pragma unroll
    for (int i = 0; i < 16; ++i) {
        vfloat2 f0 = __builtin_nontemporal_load((const vfloat2*)&src[(size_t)(2 * i + 0) * (RES * RES)]);
        vfloat2 f1 = __builtin_nontemporal_load((const vfloat2*)&src[(size_t)(2 * i + 1) * (RES * RES)]);
        float a0 = fminf(1.f, fmaxf(-1.f, f0.x));
        float a1 = fminf(1.f, fmaxf(-1.f, f1.x));
        float b0 = fminf(1.f, fmaxf(-1.f, f0.y));
        float b1 = fminf(1.f, fmaxf(-1.f, f1.y));
        pa[i] = (uint32_t)f2bf(a0) | ((uint32_t)f2bf(a1) << 16);
        pb[i] = (uint32_t)f2bf(b0) | ((uint32_t)f2bf(b1) << 16);
    }
    uint4* dst = (uint4*)(ws + (size_t)(2 * t2) * CH);
#pragma unroll
    for (int i = 0; i < 4; ++i)
        dst[i] = make_uint4(pa[4 * i], pa[4 * i + 1], pa[4 * i + 2], pa[4 * i + 3]);
#pragma unroll
    for (int i = 0; i < 4; ++i)
        dst[4 + i] = make_uint4(pb[4 * i], pb[4 * i + 1], pb[4 * i + 2], pb[4 * i + 3]);
}

// ===========================================================================
// K1 (top tier): FUSED transpose || per-block histogram.
// ===========================================================================
__global__ __launch_bounds__(1024) void k_prep(const float* __restrict__ tri,
                                               uint16_t* __restrict__ ws,
                                               const float* __restrict__ coords,
                                               uint32_t* __restrict__ bh, int M) {
    __shared__ uint32_t hl[NBIN];
    if ((int)blockIdx.x < TGRID) {
        int t2 = blockIdx.x * 1024 + threadIdx.x;
        if (t2 < NT2) transpose_body(tri, ws, t2);
        return;
    }
    int hb = blockIdx.x - TGRID;
    for (int i = threadIdx.x; i < NBIN; i += 1024) hl[i] = 0;
    __syncthreads();
    int base = hb * HBLK;
#pragma unroll
    for (int k = 0; k < HBLK / 1024; ++k) {
        int m = base + k * 1024 + threadIdx.x;
        if (m < M) {
            float cx = coords[3 * m + 0];
            float cy = coords[3 * m + 1];
            float cz = coords[3 * m + 2];
            atomicAdd(&hl[bin_of(cx, cy, cz)], 1u);
        }
    }
    __syncthreads();
    uint32_t* row = bh + (size_t)hb * NBIN;
    for (int i = threadIdx.x; i < NBIN; i += 1024) row[i] = hl[i];
}

// K2: per-bin exclusive running prefix over blocks (in place) + bin totals.
__global__ __launch_bounds__(256) void k_scan1(uint32_t* __restrict__ bh,
                                               uint32_t* __restrict__ bintotal, int nblk) {
    int j = blockIdx.x * 256 + threadIdx.x;
    if (j >= NBIN) return;
    uint32_t run = 0;
#pragma unroll 4
    for (int b = 0; b < nblk; ++b) {
        size_t idx = (size_t)b * NBIN + j;
        uint32_t c = bh[idx];
        bh[idx] = run;
        run += c;
    }
    bintotal[j] = run;
}

// K3: scatter. Per-block redundant bin-base scan in LDS, then LDS-atomic
// cursors; NT 16B writes to csort.
__global__ __launch_bounds__(1024) void k_scatter2(const float* __restrict__ coords,
                                                   const uint32_t* __restrict__ bh,
                                                   const uint32_t* __restrict__ bintotal,
                                                   float* __restrict__ csort, int M) {
    __shared__ uint32_t cur[NBIN];
    __shared__ uint32_t part[1024];
    int tid = threadIdx.x;
    int b0 = tid * 4;
    uint32_t loc[4];
    uint32_t s = 0;
#pragma unroll
    for (int k = 0; k < 4; ++k) { loc[k] = bintotal[b0 + k]; s += loc[k]; }
    part[tid] = s;
    __syncthreads();
    for (int off = 1; off < 1024; off <<= 1) {
        uint32_t v = (tid >= off) ? part[tid - off] : 0u;
        __syncthreads();
        part[tid] += v;
        __syncthreads();
    }
    uint32_t run = part[tid] - s;
    const uint32_t* row = bh + (size_t)blockIdx.x * NBIN;
#pragma unroll
    for (int k = 0; k < 4; ++k) { cur[b0 + k] = run + row[b0 + k]; run += loc[k]; }
    __syncthreads();
    int base = blockIdx.x * HBLK;
#pragma unroll
    for (int k = 0; k < HBLK / 1024; ++k) {
        int m = base + k * 1024 + threadIdx.x;
        if (m < M) {
            float cx = coords[3 * m + 0];
            float cy = coords[3 * m + 1];
            float cz = coords[3 * m + 2];
            uint32_t pos = atomicAdd(&cur[bin_of(cx, cy, cz)], 1u);   // LDS atomic
            vfloat4 v = {cx, cy, cz, __uint_as_float((uint32_t)m)};
            __builtin_nontemporal_store(v, (vfloat4*)(csort + (size_t)pos * 4));
        }
    }
}

// ---------------------------------------------------------------------------
// K4: PERSISTENT gather over SORTED points (4-lane cooperative, 1 pt/group).
// 2048 blocks (8/CU) loop over 64-point chunks. XCD k owns the contiguous
// chunk range [base_k, base_k+len_k); its 256 blocks walk it with stride 256
// => at any instant an XCD processes ~256 CONSECUTIVE chunks (tight Morton
// footprint, like the old swizzle) but waves stay resident the whole kernel
// (old one-shot blocks capped occupancy at ~32% -> latency unhidden).
// Projections (verified): p0 (cy,cx)  p1 (cz,cx)  p2 (cy,cz)
// ---------------------------------------------------------------------------
__global__ __launch_bounds__(256) void k_gather_sorted(const float* __restrict__ csort,
                                                       const uint16_t* __restrict__ tex,
                                                       float* __restrict__ out, int M) {
    int tid = threadIdx.x;
    int sub = tid & 3;
    int slot = tid >> 2;                       // 0..63: point slot within chunk
    int bid = blockIdx.x;
    int xcd = bid & 7, ib = bid >> 3;
    int nper = (int)(gridDim.x >> 3);          // blocks per XCD
    int nchunk = (M + 63) >> 6;
    int q = nchunk >> 3, r = nchunk & 7;
    int base = (xcd < r) ? xcd * (q + 1) : r * (q + 1) + (xcd - r) * q;
    int len  = q + ((xcd < r) ? 1 : 0);

    for (int t = ib; t < len; t += nper) {
        int i = (base + t) * 64 + slot;
        if (i >= M) continue;
        vfloat4 c4 = __builtin_nontemporal_load((const vfloat4*)(csort + (size_t)i * 4));
        float cx = c4.x, cy = c4.y, cz = c4.z;
        uint32_t mo = __float_as_uint(c4.w);

        float acc[8];
#pragma unroll
        for (int c = 0; c < 8; ++c) acc[c] = 0.f;

        float us[3] = {cy, cz, cy};
        float vs[3] = {cx, cx, cz};

#pragma unroll
        for (int p = 0; p < 3; ++p) {
            float px = (us[p] + 1.f) * (0.5f * (RES - 1));
            float py = (vs[p] + 1.f) * (0.5f * (RES - 1));
            float x0f = floorf(px), y0f = floorf(py);
            int x0 = (int)x0f, y0 = (int)y0f;
            float wx1 = px - x0f, wx0 = 1.f - wx1;
            float wy1 = py - y0f, wy0 = 1.f - wy1;
            int   xs[2]  = {x0, x0 + 1};
            int   ys[2]  = {y0, y0 + 1};
            float wxv[2] = {wx0, wx1};
            float wyv[2] = {wy0, wy1};
#pragma unroll
            for (int j = 0; j < 2; ++j) {
#pragma unroll
                for (int i2 = 0; i2 < 2; ++i2) {
                    int xi = xs[i2], yi = ys[j];
                    bool valid = (xi >= 0) & (xi < RES) & (yi >= 0) & (yi < RES);
                    int xc = min(max(xi, 0), RES - 1);
                    int yc = min(max(yi, 0), RES - 1);
                    float w = valid ? (wxv[i2] * wyv[j]) : 0.f;
                    const uint4* tp = (const uint4*)(tex + (((size_t)p * RES + yc) * RES + xc) * CH
                                                     + (size_t)sub * 8);
                    uint4 d = *tp;
                    uint32_t vv[4] = {d.x, d.y, d.z, d.w};
#pragma unroll
                    for (int e = 0; e < 4; ++e) {
                        union { uint32_t u; float f; } lo, hi;
                        lo.u = vv[e] << 16;
                        hi.u = vv[e] & 0xffff0000u;
                        acc[2 * e + 0] += w * lo.f;
                        acc[2 * e + 1] += w * hi.f;
                    }
                }
            }
        }

        vfloat4* dst = (vfloat4*)(out + (size_t)mo * CH + (size_t)sub * 8);
        vfloat4 v0 = {acc[0], acc[1], acc[2], acc[3]};
        vfloat4 v1 = {acc[4], acc[5], acc[6], acc[7]};
        __builtin_nontemporal_store(v0, dst);
        __builtin_nontemporal_store(v1, dst + 1);
    }
}

// ===========================================================================
// MIDDLE TIER (ws too small for blockhist): global-atomic sort.
// ===========================================================================
__global__ __launch_bounds__(256) void k_transpose(const float* __restrict__ tri,
                                                   uint16_t* __restrict__ ws) {
    int t2 = blockIdx.x * 256 + threadIdx.x;
    if (t2 < NT2) transpose_body(tri, ws, t2);
}

__global__ __launch_bounds__(256) void k_zero(uint32_t* __restrict__ hist) {
    int i = blockIdx.x * 256 + threadIdx.x;
    if (i < NBIN) hist[i] = 0;
}

__global__ __launch_bounds__(256) void k_hist(const float* __restrict__ coords,
                                              uint32_t* __restrict__ hist, int M) {
    __shared__ uint32_t hl[NBIN];
    for (int i = threadIdx.x; i < NBIN; i += 256) hl[i] = 0;
    __syncthreads();
    int base = blockIdx.x * 1024 + threadIdx.x;
#pragma unroll
    for (int k = 0; k < 4; ++k) {
        int m = base + k * 256;
        if (m < M) {
            float cx = coords[3 * m + 0];
            float cy = coords[3 * m + 1];
            float cz = coords[3 * m + 2];
            atomicAdd(&hl[bin_of(cx, cy, cz)], 1u);
        }
    }
    __syncthreads();
    for (int i = threadIdx.x; i < NBIN; i += 256) {
        uint32_t v = hl[i];
        if (v) atomicAdd(&hist[i], v);
    }
}

__global__ __launch_bounds__(256) void k_base(const uint32_t* __restrict__ hist,
                                              uint32_t* __restrict__ cursor) {
    __shared__ uint32_t part[256];
    int tid = threadIdx.x;
    int b0 = tid * (NBIN / 256);
    uint32_t loc[NBIN / 256];
    uint32_t s = 0;
#pragma unroll
    for (int k = 0; k < NBIN / 256; ++k) { loc[k] = hist[b0 + k]; s += loc[k]; }
    part[tid] = s;
    __syncthreads();
    for (int off = 1; off < 256; off <<= 1) {
        uint32_t v = (tid >= off) ? part[tid - off] : 0u;
        __syncthreads();
        part[tid] += v;
        __syncthreads();
    }
    uint32_t run = part[tid] - s;
#pragma unroll
    for (int k = 0; k < NBIN / 256; ++k) { cursor[b0 + k] = run; run += loc[k]; }
}

__global__ __launch_bounds__(256) void k_scatter(const float* __restrict__ coords,
                                                 uint32_t* __restrict__ cursor,
                                                 float4* __restrict__ csort, int M) {
    int m = blockIdx.x * 256 + threadIdx.x;
    if (m >= M) return;
    float cx = coords[3 * m + 0];
    float cy = coords[3 * m + 1];
    float cz = coords[3 * m + 2];
    uint32_t pos = atomicAdd(&cursor[bin_of(cx, cy, cz)], 1u);
    csort[pos] = make_float4(cx, cy, cz, __uint_as_float((uint32_t)m));
}

// ---------------------------------------------------------------------------
// Tier-1 gather (unsorted) — ws has room for tex only.
// ---------------------------------------------------------------------------
__global__ __launch_bounds__(256) void k_gather(const float* __restrict__ coords,
                                                const uint16_t* __restrict__ ws,
                                                float* __restrict__ out, int M) {
    int tid = threadIdx.x;
    int sub = tid & 3;
    int m = blockIdx.x * 64 + (tid >> 2);
    if (m >= M) return;
    float cx = coords[3 * m + 0];
    float cy = coords[3 * m + 1];
    float cz = coords[3 * m + 2];
    float acc[8];
#pragma unroll
    for (int c = 0; c < 8; ++c) acc[c] = 0.f;
    float us[3] = {cy, cz, cy};
    float vs[3] = {cx, cx, cz};
#pragma unroll
    for (int p = 0; p < 3; ++p) {
        float px = (us[p] + 1.f) * (0.5f * (RES - 1));
        float py = (vs[p] + 1.f) * (0.5f * (RES - 1));
        float x0f = floorf(px), y0f = floorf(py);
        int x0 = (int)x0f, y0 = (int)y0f;
        float wx1 = px - x0f, wx0 = 1.f - wx1;
        float wy1 = py - y0f, wy0 = 1.f - wy1;
        int   xs[2]  = {x0, x0 + 1};
        int   ys[2]  = {y0, y0 + 1};
        float wxv[2] = {wx0, wx1};
        float wyv[2] = {wy0, wy1};
#pragma unroll
        for (int j = 0; j < 2; ++j) {
#pragma unroll
            for (int i = 0; i < 2; ++i) {
                int xi = xs[i], yi = ys[j];
                bool valid = (xi >= 0) & (xi < RES) & (yi >= 0) & (yi < RES);
                int xc = min(max(xi, 0), RES - 1);
                int yc = min(max(yi, 0), RES - 1);
                float w = valid ? (wxv[i] * wyv[j]) : 0.f;
                const uint4* tp = (const uint4*)(ws + (((size_t)p * RES + yc) * RES + xc) * CH
                                                 + (size_t)sub * 8);
                uint4 d = *tp;
                uint32_t vv[4] = {d.x, d.y, d.z, d.w};
#pragma unroll
                for (int e = 0; e < 4; ++e) {
                    union { uint32_t u; float f; } lo, hi;
                    lo.u = vv[e] << 16;
                    hi.u = vv[e] & 0xffff0000u;
                    acc[2 * e + 0] += w * lo.f;
                    acc[2 * e + 1] += w * hi.f;
                }
            }
        }
    }
    vfloat4* dst = (vfloat4*)(out + (size_t)m * CH + (size_t)sub * 8);
    vfloat4 v0 = {acc[0], acc[1], acc[2], acc[3]};
    vfloat4 v1 = {acc[4], acc[5], acc[6], acc[7]};
    __builtin_nontemporal_store(v0, dst);
    __builtin_nontemporal_store(v1, dst + 1);
}

// ---------------------------------------------------------------------------
// Tier-0 fallback: gather straight from [3][C][R][R] fp32 (slow, correct).
// ---------------------------------------------------------------------------
__global__ __launch_bounds__(256) void k_gather_direct(const float* __restrict__ coords,
                                                       const float* __restrict__ tri,
                                                       float* __restrict__ out, int M) {
    int m = blockIdx.x * 256 + threadIdx.x;
    if (m >= M) return;
    float cx = coords[3 * m + 0];
    float cy = coords[3 * m + 1];
    float cz = coords[3 * m + 2];
    float acc[CH];
#pragma unroll
    for (int c = 0; c < CH; ++c) acc[c] = 0.f;
    float us[3] = {cy, cz, cy};
    float vs[3] = {cx, cx, cz};
    for (int p = 0; p < 3; ++p) {
        float px = (us[p] + 1.f) * (0.5f * (RES - 1));
        float py = (vs[p] + 1.f) * (0.5f * (RES - 1));
        float x0f = floorf(px), y0f = floorf(py);
        int x0 = (int)x0f, y0 = (int)y0f;
        float wx1 = px - x0f, wx0 = 1.f - wx1;
        float wy1 = py - y0f, wy0 = 1.f - wy1;
        int   xs[2]  = {x0, x0 + 1};
        int   ys[2]  = {y0, y0 + 1};
        float wxv[2] = {wx0, wx1};
        float wyv[2] = {wy0, wy1};
        for (int j = 0; j < 2; ++j)
            for (int i = 0; i < 2; ++i) {
                int xi = xs[i], yi = ys[j];
                bool valid = (xi >= 0) & (xi < RES) & (yi >= 0) & (yi < RES);
                int xc = min(max(xi, 0), RES - 1);
                int yc = min(max(yi, 0), RES - 1);
                float w = valid ? (wxv[i] * wyv[j]) : 0.f;
                const float* base = tri + ((size_t)p * CH) * RES * RES + (size_t)yc * RES + xc;
#pragma unroll
                for (int c = 0; c < CH; ++c) {
                    float v = base[(size_t)c * RES * RES];
                    v = fminf(1.f, fmaxf(-1.f, v));
                    acc[c] += w * v;
                }
            }
    }
    float4* dst = (float4*)(out + (size_t)m * CH);
#pragma unroll
    for (int i = 0; i < 8; ++i)
        dst[i] = make_float4(acc[4 * i], acc[4 * i + 1], acc[4 * i + 2], acc[4 * i + 3]);
}

extern "C" void kernel_launch(void* const* d_in, const int* in_sizes, int n_in,
                              void* d_out, int out_size, void* d_ws, size_t ws_size,
                              hipStream_t stream) {
    const float* coords = (const float*)d_in[0];   // fp32 [M,3]
    const float* tri    = (const float*)d_in[1];   // fp32 [1,3,32,512,512]
    float* out          = (float*)d_out;           // fp32 [M,32]
    int M = in_sizes[0] / 3;
    int nblk = (M + HBLK - 1) / HBLK;
    int ngather1 = (M + 63) / 64;
    int nchunk = (M + 63) / 64;
    int gblocks = (nchunk < GBLOCKS) ? ((nchunk + 7) & ~7) : GBLOCKS;
    if (gblocks < 8) gblocks = 8;

    // Top tier layout: [tex 48MiB][csort M*16][blockhist nblk*16KB][bintotal 16KB]
    size_t off_csort = TEX_BYTES;
    size_t off_bh    = off_csort + (size_t)M * 16;
    size_t off_bt    = off_bh + (size_t)nblk * NBIN * 4;
    size_t need_top  = off_bt + (size_t)NBIN * 4;

    // Middle tier layout: [tex][csort][hist][cursor]
    size_t off_hist   = off_csort + (size_t)M * 16;
    size_t off_cursor = off_hist + (size_t)NBIN * 4;
    size_t need_mid   = off_cursor + (size_t)NBIN * 4;

    if (ws_size >= need_top) {
        uint16_t* tex    = (uint16_t*)d_ws;
        float*    csort  = (float*)((char*)d_ws + off_csort);
        uint32_t* bh     = (uint32_t*)((char*)d_ws + off_bh);
        uint32_t* bt     = (uint32_t*)((char*)d_ws + off_bt);
        k_prep<<<TGRID + nblk, 1024, 0, stream>>>(tri, tex, coords, bh, M);
        k_scan1<<<(NBIN + 255) / 256, 256, 0, stream>>>(bh, bt, nblk);
        k_scatter2<<<nblk, 1024, 0, stream>>>(coords, bh, bt, csort, M);
        k_gather_sorted<<<gblocks, 256, 0, stream>>>(csort, tex, out, M);
    } else if (ws_size >= need_mid) {
        uint16_t* tex    = (uint16_t*)d_ws;
        float*    csort  = (float*)((char*)d_ws + off_csort);
        uint32_t* hist   = (uint32_t*)((char*)d_ws + off_hist);
        uint32_t* cursor = (uint32_t*)((char*)d_ws + off_cursor);
        k_transpose<<<(NT2 + 255) / 256, 256, 0, stream>>>(tri, tex);
        k_zero<<<(NBIN + 255) / 256, 256, 0, stream>>>(hist);
        k_hist<<<(M + 1023) / 1024, 256, 0, stream>>>(coords, hist, M);
        k_base<<<1, 256, 0, stream>>>(hist, cursor);
        k_scatter<<<(M + 255) / 256, 256, 0, stream>>>(coords, cursor, (float4*)csort, M);
        k_gather_sorted<<<gblocks, 256, 0, stream>>>(csort, tex, out, M);
    } else if (ws_size >= TEX_BYTES) {
        uint16_t* ws = (uint16_t*)d_ws;
        k_transpose<<<(NT2 + 255) / 256, 256, 0, stream>>>(tri, ws);
        k_gather<<<ngather1, 256, 0, stream>>>(coords, ws, out, M);
    } else {
        k_gather_direct<<<(M + 255) / 256, 256, 0, stream>>>(coords, tri, out, M);
    }
}

// Round 10
// 354.916 us; speedup vs baseline: 1.0472x; 1.0472x over previous
//
#include <hip/hip_runtime.h>
#include <hip/hip_bf16.h>
#include <stdint.h>

#define RES 512
#define CH  32
#define NP  3
#define NTEX (NP * RES * RES)                             // 786432 texels
#define NT2  (NTEX / 2)                                   // texel pairs
#define TEX_BYTES ((size_t)NTEX * CH * sizeof(uint16_t))  // 48 MiB (bf16 ws)
#define BGRID 16                                          // bins per axis
#define NBIN  (BGRID * BGRID * BGRID)                     // 4096
#define HBLK  16384                                       // points per hist/scatter block

typedef float vfloat4 __attribute__((ext_vector_type(4)));
typedef float vfloat2 __attribute__((ext_vector_type(2)));

static __device__ __forceinline__ uint16_t f2bf(float f) {
    union { float f; uint32_t u; } v; v.f = f;
    uint32_t u = v.u;
    uint32_t r = (u + 0x7fffu + ((u >> 16) & 1u)) >> 16;   // RNE
    return (uint16_t)r;
}

static __device__ __forceinline__ int binq(float c) {
    int v = (int)floorf((c + 1.f) * (BGRID * 0.5f));
    return min(BGRID - 1, max(0, v));
}
// Morton/Z-order bin id: consecutive bins are 3D neighbors -> consecutive
// gather blocks' plane footprints overlap in ALL THREE projections (L2 reuse).
static __device__ __forceinline__ uint32_t spread3(uint32_t v) {   // 4-bit -> bits 0,3,6,9
    return (v & 1u) | ((v & 2u) << 2) | ((v & 4u) << 4) | ((v & 8u) << 6);
}
static __device__ __forceinline__ int bin_of(float cx, float cy, float cz) {
    return (int)(spread3((uint32_t)binq(cx)) | (spread3((uint32_t)binq(cy)) << 1)
                 | (spread3((uint32_t)binq(cz)) << 2));
}

// Bijective XCD-chunked swizzle: blocks with bid%8==k (same XCD under
// round-robin dispatch) cover a CONTIGUOUS range of data ids. One-shot
// blocks (NOT persistent): round-8 A/B showed persistent stride-walk blocks
// drift out of phase -> footprint spreads -> FETCH +55MB, dur +15us.
static __device__ __forceinline__ int xcd_swz(int bid, int nwg) {
    int q = nwg >> 3, r = nwg & 7;
    int k = bid & 7, i = bid >> 3;
    int base = (k < r) ? k * (q + 1) : r * (q + 1) + (k - r) * q;
    return base + i;
}

// ---------------------------------------------------------------------------
// Transpose body: texel pair t2 -> [3][R][R][C] bf16, clipped.
// ---------------------------------------------------------------------------
static __device__ __forceinline__ void transpose_body(const float* __restrict__ tri,
                                                      uint16_t* __restrict__ ws, int t2) {
    int xp = t2 & (RES / 2 - 1);
    int y  = (t2 >> 8) & (RES - 1);
    int p  = t2 >> 17;
    int x  = xp * 2;
    const float* src = tri + (size_t)p * CH * RES * RES + (size_t)y * RES + x;
    uint32_t pa[16], pb[16];
#pragma unroll
    for (int i = 0; i < 16; ++i) {
        vfloat2 f0 = __builtin_nontemporal_load((const vfloat2*)&src[(size_t)(2 * i + 0) * (RES * RES)]);
        vfloat2 f1 = __builtin_nontemporal_load((const vfloat2*)&src[(size_t)(2 * i + 1) * (RES * RES)]);
        float a0 = fminf(1.f, fmaxf(-1.f, f0.x));
        float a1 = fminf(1.f, fmaxf(-1.f, f1.x));
        float b0 = fminf(1.f, fmaxf(-1.f, f0.y));
        float b1 = fminf(1.f, fmaxf(-1.f, f1.y));
        pa[i] = (uint32_t)f2bf(a0) | ((uint32_t)f2bf(a1) << 16);
        pb[i] = (uint32_t)f2bf(b0) | ((uint32_t)f2bf(b1) << 16);
    }
    uint4* dst = (uint4*)(ws + (size_t)(2 * t2) * CH);
#pragma unroll
    for (int i = 0; i < 4; ++i)
        dst[i] = make_uint4(pa[4 * i], pa[4 * i + 1], pa[4 * i + 2], pa[4 * i + 3]);
#pragma unroll
    for (int i = 0; i < 4; ++i)
        dst[4 + i] = make_uint4(pb[4 * i], pb[4 * i + 1], pb[4 * i + 2], pb[4 * i + 3]);
}

// K0: standalone transpose, 256-thread blocks (round-5 config: faster than
// the 1024-thread fused k_prep variant, which reserved dead LDS and ran
// concurrent hist blocks stealing BW — round-6 A/B: fusion cost ~+4us).
__global__ __launch_bounds__(256) void k_transpose(const float* __restrict__ tri,
                                                   uint16_t* __restrict__ ws) {
    int t2 = blockIdx.x * 256 + threadIdx.x;
    if (t2 < NT2) transpose_body(tri, ws, t2);
}

// K1: per-block LDS histogram -> blockhist rows (plain stores, no global
// atomics).
__global__ __launch_bounds__(1024) void k_hist2(const float* __restrict__ coords,
                                                uint32_t* __restrict__ bh, int M) {
    __shared__ uint32_t hl[NBIN];
    for (int i = threadIdx.x; i < NBIN; i += 1024) hl[i] = 0;
    __syncthreads();
    int base = blockIdx.x * HBLK;
#pragma unroll
    for (int k = 0; k < HBLK / 1024; ++k) {
        int m = base + k * 1024 + threadIdx.x;
        if (m < M) {
            float cx = coords[3 * m + 0];
            float cy = coords[3 * m + 1];
            float cz = coords[3 * m + 2];
            atomicAdd(&hl[bin_of(cx, cy, cz)], 1u);
        }
    }
    __syncthreads();
    uint32_t* row = bh + (size_t)blockIdx.x * NBIN;
    for (int i = threadIdx.x; i < NBIN; i += 1024) row[i] = hl[i];
}

// K2: per-bin exclusive running prefix over blocks (in place) + bin totals.
__global__ __launch_bounds__(256) void k_scan1(uint32_t* __restrict__ bh,
                                               uint32_t* __restrict__ bintotal, int nblk) {
    int j = blockIdx.x * 256 + threadIdx.x;
    if (j >= NBIN) return;
    uint32_t run = 0;
#pragma unroll 4
    for (int b = 0; b < nblk; ++b) {
        size_t idx = (size_t)b * NBIN + j;
        uint32_t c = bh[idx];
        bh[idx] = run;
        run += c;
    }
    bintotal[j] = run;
}

// K3: scatter. Per-block redundant bin-base scan in LDS (folds the serial
// k_base dispatch), then LDS-atomic cursors; NT 16B writes to csort.
__global__ __launch_bounds__(1024) void k_scatter2(const float* __restrict__ coords,
                                                   const uint32_t* __restrict__ bh,
                                                   const uint32_t* __restrict__ bintotal,
                                                   float* __restrict__ csort, int M) {
    __shared__ uint32_t cur[NBIN];
    __shared__ uint32_t part[1024];
    int tid = threadIdx.x;
    int b0 = tid * 4;
    uint32_t loc[4];
    uint32_t s = 0;
#pragma unroll
    for (int k = 0; k < 4; ++k) { loc[k] = bintotal[b0 + k]; s += loc[k]; }
    part[tid] = s;
    __syncthreads();
    for (int off = 1; off < 1024; off <<= 1) {
        uint32_t v = (tid >= off) ? part[tid - off] : 0u;
        __syncthreads();
        part[tid] += v;
        __syncthreads();
    }
    uint32_t run = part[tid] - s;
    const uint32_t* row = bh + (size_t)blockIdx.x * NBIN;
#pragma unroll
    for (int k = 0; k < 4; ++k) { cur[b0 + k] = run + row[b0 + k]; run += loc[k]; }
    __syncthreads();
    int base = blockIdx.x * HBLK;
#pragma unroll
    for (int k = 0; k < HBLK / 1024; ++k) {
        int m = base + k * 1024 + threadIdx.x;
        if (m < M) {
            float cx = coords[3 * m + 0];
            float cy = coords[3 * m + 1];
            float cz = coords[3 * m + 2];
            uint32_t pos = atomicAdd(&cur[bin_of(cx, cy, cz)], 1u);   // LDS atomic
            vfloat4 v = {cx, cy, cz, __uint_as_float((uint32_t)m)};
            __builtin_nontemporal_store(v, (vfloat4*)(csort + (size_t)pos * 4));
        }
    }
}

// ---------------------------------------------------------------------------
// K4: gather over SORTED points — EXACT round-6 config (proven 92us):
// one-shot 64-pt blocks, 4-lane cooperative, XCD-chunked swizzle, NT csort
// load, NT out stores. Per the revised model this is within a few percent
// of the scattered-DRAM ceiling (95MB semi-random fetch + 145MB scattered
// 128B writes at ~45% DRAM efficiency ~= 92us); occupancy/ILP levers were
// refuted in rounds 7-8.
// Projections (verified): p0 (cy,cx)  p1 (cz,cx)  p2 (cy,cz)
// ---------------------------------------------------------------------------
__global__ __launch_bounds__(256) void k_gather_sorted(const float* __restrict__ csort,
                                                       const uint16_t* __restrict__ tex,
                                                       float* __restrict__ out, int M) {
    int tid = threadIdx.x;
    int sub = tid & 3;
    int data = xcd_swz(blockIdx.x, gridDim.x);
    int i = data * 64 + (tid >> 2);
    if (i >= M) return;
    vfloat4 c4 = __builtin_nontemporal_load((const vfloat4*)(csort + (size_t)i * 4));
    float cx = c4.x, cy = c4.y, cz = c4.z;
    uint32_t mo = __float_as_uint(c4.w);

    float acc[8];
#pragma unroll
    for (int c = 0; c < 8; ++c) acc[c] = 0.f;

    float us[3] = {cy, cz, cy};
    float vs[3] = {cx, cx, cz};

#pragma unroll
    for (int p = 0; p < 3; ++p) {
        float px = (us[p] + 1.f) * (0.5f * (RES - 1));
        float py = (vs[p] + 1.f) * (0.5f * (RES - 1));
        float x0f = floorf(px), y0f = floorf(py);
        int x0 = (int)x0f, y0 = (int)y0f;
        float wx1 = px - x0f, wx0 = 1.f - wx1;
        float wy1 = py - y0f, wy0 = 1.f - wy1;
        int   xs[2]  = {x0, x0 + 1};
        int   ys[2]  = {y0, y0 + 1};
        float wxv[2] = {wx0, wx1};
        float wyv[2] = {wy0, wy1};
#pragma unroll
        for (int j = 0; j < 2; ++j) {
#pragma unroll
            for (int i2 = 0; i2 < 2; ++i2) {
                int xi = xs[i2], yi = ys[j];
                bool valid = (xi >= 0) & (xi < RES) & (yi >= 0) & (yi < RES);
                int xc = min(max(xi, 0), RES - 1);
                int yc = min(max(yi, 0), RES - 1);
                float w = valid ? (wxv[i2] * wyv[j]) : 0.f;
                const uint4* tp = (const uint4*)(tex + (((size_t)p * RES + yc) * RES + xc) * CH
                                                 + (size_t)sub * 8);
                uint4 d = *tp;
                uint32_t vv[4] = {d.x, d.y, d.z, d.w};
#pragma unroll
                for (int e = 0; e < 4; ++e) {
                    union { uint32_t u; float f; } lo, hi;
                    lo.u = vv[e] << 16;
                    hi.u = vv[e] & 0xffff0000u;
                    acc[2 * e + 0] += w * lo.f;
                    acc[2 * e + 1] += w * hi.f;
                }
            }
        }
    }

    vfloat4* dst = (vfloat4*)(out + (size_t)mo * CH + (size_t)sub * 8);
    vfloat4 v0 = {acc[0], acc[1], acc[2], acc[3]};
    vfloat4 v1 = {acc[4], acc[5], acc[6], acc[7]};
    __builtin_nontemporal_store(v0, dst);
    __builtin_nontemporal_store(v1, dst + 1);
}

// ===========================================================================
// MIDDLE TIER (ws too small for blockhist): global-atomic sort.
// ===========================================================================
__global__ __launch_bounds__(256) void k_zero(uint32_t* __restrict__ hist) {
    int i = blockIdx.x * 256 + threadIdx.x;
    if (i < NBIN) hist[i] = 0;
}

__global__ __launch_bounds__(256) void k_hist(const float* __restrict__ coords,
                                              uint32_t* __restrict__ hist, int M) {
    __shared__ uint32_t hl[NBIN];
    for (int i = threadIdx.x; i < NBIN; i += 256) hl[i] = 0;
    __syncthreads();
    int base = blockIdx.x * 1024 + threadIdx.x;
#pragma unroll
    for (int k = 0; k < 4; ++k) {
        int m = base + k * 256;
        if (m < M) {
            float cx = coords[3 * m + 0];
            float cy = coords[3 * m + 1];
            float cz = coords[3 * m + 2];
            atomicAdd(&hl[bin_of(cx, cy, cz)], 1u);
        }
    }
    __syncthreads();
    for (int i = threadIdx.x; i < NBIN; i += 256) {
        uint32_t v = hl[i];
        if (v) atomicAdd(&hist[i], v);
    }
}

__global__ __launch_bounds__(256) void k_base(const uint32_t* __restrict__ hist,
                                              uint32_t* __restrict__ cursor) {
    __shared__ uint32_t part[256];
    int tid = threadIdx.x;
    int b0 = tid * (NBIN / 256);
    uint32_t loc[NBIN / 256];
    uint32_t s = 0;
#pragma unroll
    for (int k = 0; k < NBIN / 256; ++k) { loc[k] = hist[b0 + k]; s += loc[k]; }
    part[tid] = s;
    __syncthreads();
    for (int off = 1; off < 256; off <<= 1) {
        uint32_t v = (tid >= off) ? part[tid - off] : 0u;
        __syncthreads();
        part[tid] += v;
        __syncthreads();
    }
    uint32_t run = part[tid] - s;
#pragma unroll
    for (int k = 0; k < NBIN / 256; ++k) { cursor[b0 + k] = run; run += loc[k]; }
}

__global__ __launch_bounds__(256) void k_scatter(const float* __restrict__ coords,
                                                 uint32_t* __restrict__ cursor,
                                                 float4* __restrict__ csort, int M) {
    int m = blockIdx.x * 256 + threadIdx.x;
    if (m >= M) return;
    float cx = coords[3 * m + 0];
    float cy = coords[3 * m + 1];
    float cz = coords[3 * m + 2];
    uint32_t pos = atomicAdd(&cursor[bin_of(cx, cy, cz)], 1u);
    csort[pos] = make_float4(cx, cy, cz, __uint_as_float((uint32_t)m));
}

// ---------------------------------------------------------------------------
// Tier-1 gather (unsorted) — ws has room for tex only.
// ---------------------------------------------------------------------------
__global__ __launch_bounds__(256) void k_gather(const float* __restrict__ coords,
                                                const uint16_t* __restrict__ ws,
                                                float* __restrict__ out, int M) {
    int tid = threadIdx.x;
    int sub = tid & 3;
    int m = blockIdx.x * 64 + (tid >> 2);
    if (m >= M) return;
    float cx = coords[3 * m + 0];
    float cy = coords[3 * m + 1];
    float cz = coords[3 * m + 2];
    float acc[8];
#pragma unroll
    for (int c = 0; c < 8; ++c) acc[c] = 0.f;
    float us[3] = {cy, cz, cy};
    float vs[3] = {cx, cx, cz};
#pragma unroll
    for (int p = 0; p < 3; ++p) {
        float px = (us[p] + 1.f) * (0.5f * (RES - 1));
        float py = (vs[p] + 1.f) * (0.5f * (RES - 1));
        float x0f = floorf(px), y0f = floorf(py);
        int x0 = (int)x0f, y0 = (int)y0f;
        float wx1 = px - x0f, wx0 = 1.f - wx1;
        float wy1 = py - y0f, wy0 = 1.f - wy1;
        int   xs[2]  = {x0, x0 + 1};
        int   ys[2]  = {y0, y0 + 1};
        float wxv[2] = {wx0, wx1};
        float wyv[2] = {wy0, wy1};
#pragma unroll
        for (int j = 0; j < 2; ++j) {
#pragma unroll
            for (int i = 0; i < 2; ++i) {
                int xi = xs[i], yi = ys[j];
                bool valid = (xi >= 0) & (xi < RES) & (yi >= 0) & (yi < RES);
                int xc = min(max(xi, 0), RES - 1);
                int yc = min(max(yi, 0), RES - 1);
                float w = valid ? (wxv[i] * wyv[j]) : 0.f;
                const uint4* tp = (const uint4*)(ws + (((size_t)p * RES + yc) * RES + xc) * CH
                                                 + (size_t)sub * 8);
                uint4 d = *tp;
                uint32_t vv[4] = {d.x, d.y, d.z, d.w};
#pragma unroll
                for (int e = 0; e < 4; ++e) {
                    union { uint32_t u; float f; } lo, hi;
                    lo.u = vv[e] << 16;
                    hi.u = vv[e] & 0xffff0000u;
                    acc[2 * e + 0] += w * lo.f;
                    acc[2 * e + 1] += w * hi.f;
                }
            }
        }
    }
    vfloat4* dst = (vfloat4*)(out + (size_t)m * CH + (size_t)sub * 8);
    vfloat4 v0 = {acc[0], acc[1], acc[2], acc[3]};
    vfloat4 v1 = {acc[4], acc[5], acc[6], acc[7]};
    __builtin_nontemporal_store(v0, dst);
    __builtin_nontemporal_store(v1, dst + 1);
}

// ---------------------------------------------------------------------------
// Tier-0 fallback: gather straight from [3][C][R][R] fp32 (slow, correct).
// ---------------------------------------------------------------------------
__global__ __launch_bounds__(256) void k_gather_direct(const float* __restrict__ coords,
                                                       const float* __restrict__ tri,
                                                       float* __restrict__ out, int M) {
    int m = blockIdx.x * 256 + threadIdx.x;
    if (m >= M) return;
    float cx = coords[3 * m + 0];
    float cy = coords[3 * m + 1];
    float cz = coords[3 * m + 2];
    float acc[CH];
#pragma unroll
    for (int c = 0; c < CH; ++c) acc[c] = 0.f;
    float us[3] = {cy, cz, cy};
    float vs[3] = {cx, cx, cz};
    for (int p = 0; p < 3; ++p) {
        float px = (us[p] + 1.f) * (0.5f * (RES - 1));
        float py = (vs[p] + 1.f) * (0.5f * (RES - 1));
        float x0f = floorf(px), y0f = floorf(py);
        int x0 = (int)x0f, y0 = (int)y0f;
        float wx1 = px - x0f, wx0 = 1.f - wx1;
        float wy1 = py - y0f, wy0 = 1.f - wy1;
        int   xs[2]  = {x0, x0 + 1};
        int   ys[2]  = {y0, y0 + 1};
        float wxv[2] = {wx0, wx1};
        float wyv[2] = {wy0, wy1};
        for (int j = 0; j < 2; ++j)
            for (int i = 0; i < 2; ++i) {
                int xi = xs[i], yi = ys[j];
                bool valid = (xi >= 0) & (xi < RES) & (yi >= 0) & (yi < RES);
                int xc = min(max(xi, 0), RES - 1);
                int yc = min(max(yi, 0), RES - 1);
                float w = valid ? (wxv[i] * wyv[j]) : 0.f;
                const float* base = tri + ((size_t)p * CH) * RES * RES + (size_t)yc * RES + xc;
#pragma unroll
                for (int c = 0; c < CH; ++c) {
                    float v = base[(size_t)c * RES * RES];
                    v = fminf(1.f, fmaxf(-1.f, v));
                    acc[c] += w * v;
                }
            }
    }
    float4* dst = (float4*)(out + (size_t)m * CH);
#pragma unroll
    for (int i = 0; i < 8; ++i)
        dst[i] = make_float4(acc[4 * i], acc[4 * i + 1], acc[4 * i + 2], acc[4 * i + 3]);
}

extern "C" void kernel_launch(void* const* d_in, const int* in_sizes, int n_in,
                              void* d_out, int out_size, void* d_ws, size_t ws_size,
                              hipStream_t stream) {
    const float* coords = (const float*)d_in[0];   // fp32 [M,3]
    const float* tri    = (const float*)d_in[1];   // fp32 [1,3,32,512,512]
    float* out          = (float*)d_out;           // fp32 [M,32]
    int M = in_sizes[0] / 3;
    int nblk = (M + HBLK - 1) / HBLK;
    int ngather = (M + 63) / 64;

    // Top tier layout: [tex 48MiB][csort M*16][blockhist nblk*16KB][bintotal 16KB]
    size_t off_csort = TEX_BYTES;
    size_t off_bh    = off_csort + (size_t)M * 16;
    size_t off_bt    = off_bh + (size_t)nblk * NBIN * 4;
    size_t need_top  = off_bt + (size_t)NBIN * 4;

    // Middle tier layout: [tex][csort][hist][cursor]
    size_t off_hist   = off_csort + (size_t)M * 16;
    size_t off_cursor = off_hist + (size_t)NBIN * 4;
    size_t need_mid   = off_cursor + (size_t)NBIN * 4;

    if (ws_size >= need_top) {
        uint16_t* tex    = (uint16_t*)d_ws;
        float*    csort  = (float*)((char*)d_ws + off_csort);
        uint32_t* bh     = (uint32_t*)((char*)d_ws + off_bh);
        uint32_t* bt     = (uint32_t*)((char*)d_ws + off_bt);
        k_transpose<<<(NT2 + 255) / 256, 256, 0, stream>>>(tri, tex);
        k_hist2<<<nblk, 1024, 0, stream>>>(coords, bh, M);
        k_scan1<<<(NBIN + 255) / 256, 256, 0, stream>>>(bh, bt, nblk);
        k_scatter2<<<nblk, 1024, 0, stream>>>(coords, bh, bt, csort, M);
        k_gather_sorted<<<ngather, 256, 0, stream>>>(csort, tex, out, M);
    } else if (ws_size >= need_mid) {
        uint16_t* tex    = (uint16_t*)d_ws;
        float*    csort  = (float*)((char*)d_ws + off_csort);
        uint32_t* hist   = (uint32_t*)((char*)d_ws + off_hist);
        uint32_t* cursor = (uint32_t*)((char*)d_ws + off_cursor);
        k_transpose<<<(NT2 + 255) / 256, 256, 0, stream>>>(tri, tex);
        k_zero<<<(NBIN + 255) / 256, 256, 0, stream>>>(hist);
        k_hist<<<(M + 1023) / 1024, 256, 0, stream>>>(coords, hist, M);
        k_base<<<1, 256, 0, stream>>>(hist, cursor);
        k_scatter<<<(M + 255) / 256, 256, 0, stream>>>(coords, cursor, (float4*)csort, M);
        k_gather_sorted<<<ngather, 256, 0, stream>>>(csort, tex, out, M);
    } else if (ws_size >= TEX_BYTES) {
        uint16_t* ws = (uint16_t*)d_ws;
        k_transpose<<<(NT2 + 255) / 256, 256, 0, stream>>>(tri, ws);
        k_gather<<<ngather, 256, 0, stream>>>(coords, ws, out, M);
    } else {
        k_gather_direct<<<(M + 255) / 256, 256, 0, stream>>>(coords, tri, out, M);
    }
}